// Round 8
// baseline (72.995 us; speedup 1.0000x reference)
//
#include <hip/hip_runtime.h>
#include <hip/hip_bf16.h>

typedef __attribute__((ext_vector_type(8))) short short8;
typedef __attribute__((ext_vector_type(4))) float f32x4;
typedef __attribute__((ext_vector_type(4))) unsigned int u32x4;
typedef __attribute__((ext_vector_type(4))) unsigned short u16x4;
typedef unsigned short u16;

#define MFMA16 __builtin_amdgcn_mfma_f32_16x16x32_bf16

__device__ __forceinline__ u16 f2bf(float x) {
    unsigned int u = __builtin_bit_cast(unsigned int, x);
    u = (u + 0x7FFFu + ((u >> 16) & 1u)) >> 16;
    return (u16)u;
}

constexpr int N_TOK = 4096;
constexpr int DH = 64;
constexpr int NH = 16;
constexpr int NTP = N_TOK + 32;   // V^T row stride in keys (pad zeroed -> safe tile overhang)
constexpr float SCALE = 0.125f;
constexpr float SHIFT = 8.0f;     // fixed softmax shift; exp(s-8), sums merge additively
constexpr float MASKVAL = -1e30f;

// ============================ PREPASS (unchanged, proven) ==================
__global__ __launch_bounds__(256)
void doc_prep(const float* __restrict__ Kg, const float* __restrict__ Vg,
              const int* __restrict__ doc, u16* __restrict__ Kbf,
              u16* __restrict__ Vtb, int* __restrict__ bnds) {
    const int b = blockIdx.x;
    const int tid = threadIdx.x;
    if (b < 2048) {
        __shared__ u16 tile[DH][40];
        const int h = b >> 7, k0 = (b & 127) * 32;
        #pragma unroll
        for (int i = 0; i < 2; ++i) {
            const int idx = tid + i * 256;
            const int r = idx >> 4, c = (idx & 15) * 4;
            const float4 f = *(const float4*)&Vg[((size_t)h * N_TOK + k0 + r) * DH + c];
            tile[c + 0][r] = f2bf(f.x); tile[c + 1][r] = f2bf(f.y);
            tile[c + 2][r] = f2bf(f.z); tile[c + 3][r] = f2bf(f.w);
        }
        __syncthreads();
        #pragma unroll
        for (int i = 0; i < 2; ++i) {
            const int idx = tid + i * 256;
            const int d = idx >> 3, kq = (idx & 7) * 4;
            u16x4 o;
            o[0] = tile[d][kq + 0]; o[1] = tile[d][kq + 1];
            o[2] = tile[d][kq + 2]; o[3] = tile[d][kq + 3];
            *(u16x4*)&Vtb[((size_t)h * DH + d) * NTP + k0 + kq] = o;
        }
        if ((b & 127) == 127) {
            for (int i = tid; i < DH * 8; i += 256) {
                const int d = i >> 3, kq = (i & 7) * 4;
                u16x4 z; z[0] = 0; z[1] = 0; z[2] = 0; z[3] = 0;
                *(u16x4*)&Vtb[((size_t)h * DH + d) * NTP + N_TOK + kq] = z;
            }
        }
    } else if (b < 4096) {
        const int bb = b - 2048;
        const int h = bb >> 7, k0 = (bb & 127) * 32;
        #pragma unroll
        for (int i = 0; i < 2; ++i) {
            const int idx = tid + i * 256;
            const int r = idx >> 4, c = (idx & 15) * 4;
            const float4 f = *(const float4*)&Kg[((size_t)h * N_TOK + k0 + r) * DH + c];
            u16x4 o;
            o[0] = f2bf(f.x); o[1] = f2bf(f.y); o[2] = f2bf(f.z); o[3] = f2bf(f.w);
            *(u16x4*)&Kbf[((size_t)h * N_TOK + k0 + r) * DH + c] = o;
        }
    } else {
        if (tid < 17) bnds[tid] = N_TOK;
        __syncthreads();
        const int i0 = tid * 16;
        int prev = (i0 == 0) ? -1 : doc[i0 - 1];
        for (int j = 0; j < 16; ++j) {
            const int cur = doc[i0 + j];
            for (int dd = prev + 1; dd <= cur; ++dd) bnds[dd] = i0 + j;
            prev = cur;
        }
    }
}

// ============================ MAIN (v19) ==================================
// v18 (barrier-free, L2-direct) + software pipelining: K and V tile fragments
// double-buffered in registers with distance-1 prefetch, explicit 2x-unrolled
// ping-pong (named reg sets -> no dynamic indexing, no rotation movs). Loads
// for tile t+1 issue before tile t's compute; first use is one full tile of
// MFMA+VALU later, covering the ~200-400cy L2 latency that made v18
// latency-bound (VALUBusy 13.5%).
__global__ __launch_bounds__(64, 4)
void doc_attn_v19(const float* __restrict__ Qg, const u16* __restrict__ Kbf,
                  const u16* __restrict__ Vtb, const int* __restrict__ bnds,
                  float* __restrict__ Out) {
    const int b = blockIdx.x;                       // 0..4095
    const int swz = ((b & 7) << 9) | (b >> 3);      // XCD-chunked (4096 = 8*512)
    const int h = swz >> 8;                         // 0..15
    const int dI = (swz >> 4) & 15;                 // doc id
    const int slot = swz & 15;                      // q-group slot
    const int lane = threadIdx.x;                   // 0..63
    const int l15 = lane & 15;
    const int lg = lane >> 4;

    const int qs = bnds[dI], qe = bnds[dI + 1];
    const int len = qe - qs;
    if (len <= 0) return;
    const int nG = (len + 15) >> 4;
    if (slot >= nG) return;

    const int src0 = l15 + ((lane & 16) << 1);      // P^T exchange (v9-validated)
    const int src1 = src0 + 16;
    const bool khsel = (lg >> 1) != 0;

    const int abs0 = qs & ~31;                      // aligned tile origin
    const int ctiles = (qe - abs0 + 31) >> 5;

    const u16* Kbase = Kbf + (size_t)h * N_TOK * DH + lg * 8;
    const u16* Vbase = Vtb + ((size_t)h * DH + l15) * NTP + lg * 8;

    for (int g = slot; g < nG; g += 16) {
        // Q fragment (fp32 -> bf16, SCALE folded)
        short8 aq[2];
        {
            const int qrow = min(qs + g * 16 + l15, N_TOK - 1);  // clamp; never stored
            const float* qp = &Qg[((size_t)h * N_TOK + qrow) * DH + lg * 8];
            #pragma unroll
            for (int kc = 0; kc < 2; ++kc) {
                float4 f0 = *(const float4*)(qp + kc * 32);
                float4 f1 = *(const float4*)(qp + kc * 32 + 4);
                short8 a;
                a[0]=(short)f2bf(f0.x*SCALE); a[1]=(short)f2bf(f0.y*SCALE);
                a[2]=(short)f2bf(f0.z*SCALE); a[3]=(short)f2bf(f0.w*SCALE);
                a[4]=(short)f2bf(f1.x*SCALE); a[5]=(short)f2bf(f1.y*SCALE);
                a[6]=(short)f2bf(f1.z*SCALE); a[7]=(short)f2bf(f1.w*SCALE);
                aq[kc] = a;
            }
        }

        f32x4 o_acc[4];
        float lsum = 0.f;
        #pragma unroll
        for (int db = 0; db < 4; ++db) o_acc[db] = (f32x4){0.f, 0.f, 0.f, 0.f};

        auto loadK = [&](int tt, short8& k00, short8& k01, short8& k10, short8& k11) {
            const int kb_ = abs0 + (tt << 5);
            const int kr0 = min(kb_ + l15, N_TOK - 1);
            const int kr1 = min(kb_ + 16 + l15, N_TOK - 1);
            const u16* kp0 = Kbase + (size_t)kr0 * DH;
            const u16* kp1 = Kbase + (size_t)kr1 * DH;
            k00 = *(const short8*)(kp0);
            k01 = *(const short8*)(kp0 + 32);
            k10 = *(const short8*)(kp1);
            k11 = *(const short8*)(kp1 + 32);
        };
        auto loadV = [&](int tt, short8& v0, short8& v1, short8& v2, short8& v3) {
            const int kb_ = abs0 + (tt << 5);
            v0 = *(const short8*)(Vbase + (size_t)(0 * 16) * NTP + kb_);
            v1 = *(const short8*)(Vbase + (size_t)(1 * 16) * NTP + kb_);
            v2 = *(const short8*)(Vbase + (size_t)(2 * 16) * NTP + kb_);
            v3 = *(const short8*)(Vbase + (size_t)(3 * 16) * NTP + kb_);
        };
        auto compute = [&](int tt, short8 k00, short8 k01, short8 k10, short8 k11,
                           short8 v0, short8 v1, short8 v2, short8 v3) {
            const int kb = abs0 + (tt << 5);
            // swapped QK^T: lane holds S[q=l15][key=kb+kh*16+lg*4+i] - 8
            f32x4 sa0 = (f32x4){-SHIFT, -SHIFT, -SHIFT, -SHIFT};
            f32x4 sa1 = (f32x4){-SHIFT, -SHIFT, -SHIFT, -SHIFT};
            __builtin_amdgcn_s_setprio(1);
            sa0 = MFMA16(k00, aq[0], sa0, 0, 0, 0);
            sa0 = MFMA16(k01, aq[1], sa0, 0, 0, 0);
            sa1 = MFMA16(k10, aq[0], sa1, 0, 0, 0);
            sa1 = MFMA16(k11, aq[1], sa1, 0, 0, 0);
            __builtin_amdgcn_s_setprio(0);

            // fixed-shift softmax; two-sided doc mask (absolute keys)
            float p0[4], p1[4];
            #pragma unroll
            for (int i = 0; i < 4; ++i) {
                const int key0 = kb + lg * 4 + i;
                const int key1 = key0 + 16;
                const float x0 = (key0 >= qs && key0 < qe) ? sa0[i] : MASKVAL;
                const float x1 = (key1 >= qs && key1 < qe) ? sa1[i] : MASKVAL;
                p0[i] = __expf(x0);
                p1[i] = __expf(x1);
                lsum += p0[i] + p1[i];
            }

            // P^T B-fragment via f2bf pack + cross-lg shuffles (v9-validated)
            const unsigned int a0 = (unsigned int)f2bf(p0[0]) | ((unsigned int)f2bf(p0[1]) << 16);
            const unsigned int a1 = (unsigned int)f2bf(p0[2]) | ((unsigned int)f2bf(p0[3]) << 16);
            const unsigned int b0w = (unsigned int)f2bf(p1[0]) | ((unsigned int)f2bf(p1[1]) << 16);
            const unsigned int b1w = (unsigned int)f2bf(p1[2]) | ((unsigned int)f2bf(p1[3]) << 16);
            const unsigned int t00 = __shfl((int)a0, src0);
            const unsigned int t01 = __shfl((int)a1, src0);
            const unsigned int t10 = __shfl((int)b0w, src0);
            const unsigned int t11 = __shfl((int)b1w, src0);
            const unsigned int u00 = __shfl((int)a0, src1);
            const unsigned int u01 = __shfl((int)a1, src1);
            const unsigned int u10 = __shfl((int)b0w, src1);
            const unsigned int u11 = __shfl((int)b1w, src1);
            u32x4 af;
            af[0] = khsel ? t10 : t00;
            af[1] = khsel ? t11 : t01;
            af[2] = khsel ? u10 : u00;
            af[3] = khsel ? u11 : u01;
            const short8 pa = __builtin_bit_cast(short8, af);

            // PV: O^T = mfma(A=V^T, B=P^T)
            __builtin_amdgcn_s_setprio(1);
            o_acc[0] = MFMA16(v0, pa, o_acc[0], 0, 0, 0);
            o_acc[1] = MFMA16(v1, pa, o_acc[1], 0, 0, 0);
            o_acc[2] = MFMA16(v2, pa, o_acc[2], 0, 0, 0);
            o_acc[3] = MFMA16(v3, pa, o_acc[3], 0, 0, 0);
            __builtin_amdgcn_s_setprio(0);
        };

        // ---- pipelined tile loop: ping-pong reg sets A/B, prefetch dist 1 ----
        short8 ak00, ak01, ak10, ak11, av0, av1, av2, av3;
        short8 bk00, bk01, bk10, bk11, bv0, bv1, bv2, bv3;
        loadK(0, ak00, ak01, ak10, ak11);
        loadV(0, av0, av1, av2, av3);
        int t = 0;
        for (; t + 2 <= ctiles; t += 2) {
            loadK(t + 1, bk00, bk01, bk10, bk11);   // in flight during compute(t)
            loadV(t + 1, bv0, bv1, bv2, bv3);
            compute(t, ak00, ak01, ak10, ak11, av0, av1, av2, av3);
            if (t + 2 < ctiles) {
                loadK(t + 2, ak00, ak01, ak10, ak11);  // in flight during compute(t+1)
                loadV(t + 2, av0, av1, av2, av3);
            }
            compute(t + 1, bk00, bk01, bk10, bk11, bv0, bv1, bv2, bv3);
        }
        if (t < ctiles)   // odd tail: A-set holds tile t
            compute(t, ak00, ak01, ak10, ak11, av0, av1, av2, av3);

        // ---- epilogue: row-sum reduce (lanes share q across lg) ----
        float rs = lsum;
        rs += __shfl_xor(rs, 16);
        rs += __shfl_xor(rs, 32);
        const float inv = 1.0f / rs;
        const int qrow = qs + g * 16 + l15;
        if (qrow < qe) {
            float* op = &Out[((size_t)h * N_TOK + qrow) * DH + lg * 4];
            #pragma unroll
            for (int db = 0; db < 4; ++db) {
                float4 v;
                v.x = o_acc[db][0] * inv;
                v.y = o_acc[db][1] * inv;
                v.z = o_acc[db][2] * inv;
                v.w = o_acc[db][3] * inv;
                *(float4*)(op + db * 16) = v;
            }
        }
    }
}

// ==================== FALLBACK (v16 verbatim, 41.6us) =====================
constexpr int KMAXF = 128;
constexpr int KSTF = 72;
constexpr int VSTF = 136;

__global__ __launch_bounds__(512, 4)
void doc_attn_v16(const float* __restrict__ Qg, const float* __restrict__ Kg,
                  const float* __restrict__ Vg, const int* __restrict__ doc,
                  float* __restrict__ Out) {
    __shared__ __align__(16) u16 Klds[KMAXF][KSTF];
    __shared__ __align__(16) u16 Vtld[DH][VSTF];
    __shared__ int bnd[2];

    const int bid = blockIdx.x;
    const int swz = ((bid & 7) << 7) | (bid >> 3);
    const int h = swz >> 6;
    const int dI = (swz >> 2) & 15;
    const int qq = swz & 3;
    const int tid = threadIdx.x;
    const int lane = tid & 63;
    const int w = tid >> 6;
    const int l15 = lane & 15;
    const int lg = lane >> 4;

    if (tid == 0) { bnd[0] = N_TOK; bnd[1] = N_TOK; }
    __syncthreads();
    {
        const int i0 = tid * 8;
        int prev = (i0 == 0) ? -1 : doc[i0 - 1];
        #pragma unroll
        for (int j = 0; j < 8; ++j) {
            const int cur = doc[i0 + j];
            if (cur >= dI && prev < dI) bnd[0] = i0 + j;
            if (cur >= dI + 1 && prev < dI + 1) bnd[1] = i0 + j;
            prev = cur;
        }
    }
    __syncthreads();
    const int qs = bnd[0], qe = bnd[1];
    const int len = qe - qs;
    if (len <= 0) return;

    const int nG = (len + 15) >> 4;
    const int nGq = (nG + 3) >> 2;
    const int gBeg = qq * nGq;
    const int gEnd = min(nG, gBeg + nGq);
    if (gBeg >= gEnd) return;

    const int src0 = l15 + ((lane & 16) << 1);
    const int src1 = src0 + 16;
    const bool khsel = (lg >> 1) != 0;

    for (int g0 = gBeg; g0 < gEnd; g0 += 8) {
        const int g = g0 + w;
        const int gid = (g < gEnd) ? g : -1;
        short8 aq[2];
        {
            const int gl = (g < gEnd) ? g : 0;
            const int qrow = min(qs + gl * 16 + l15, N_TOK - 1);
            const float* qp = &Qg[((size_t)h * N_TOK + qrow) * DH + lg * 8];
            #pragma unroll
            for (int kc = 0; kc < 2; ++kc) {
                float4 f0 = *(const float4*)(qp + kc * 32);
                float4 f1 = *(const float4*)(qp + kc * 32 + 4);
                short8 a;
                a[0]=(short)f2bf(f0.x*SCALE); a[1]=(short)f2bf(f0.y*SCALE);
                a[2]=(short)f2bf(f0.z*SCALE); a[3]=(short)f2bf(f0.w*SCALE);
                a[4]=(short)f2bf(f1.x*SCALE); a[5]=(short)f2bf(f1.y*SCALE);
                a[6]=(short)f2bf(f1.z*SCALE); a[7]=(short)f2bf(f1.w*SCALE);
                aq[kc] = a;
            }
        }

        f32x4 o_acc[4];
        float lsum = 0.f;
        #pragma unroll
        for (int db = 0; db < 4; ++db) o_acc[db] = (f32x4){0.f, 0.f, 0.f, 0.f};

        for (int c0 = 0; c0 < len; c0 += KMAXF) {
            const int clen = min(KMAXF, len - c0);
            const int ctiles = (clen + 31) >> 5;
            const int cl32 = ctiles << 5;

            __syncthreads();

            for (int idx = tid; idx < clen * 16; idx += 512) {
                const int r = idx >> 4, c = (idx & 15) * 4;
                const float4 kf = *(const float4*)&Kg[((size_t)h * N_TOK + qs + c0 + r) * DH + c];
                const float4 vf = *(const float4*)&Vg[((size_t)h * N_TOK + qs + c0 + r) * DH + c];
                u16x4 o4;
                o4[0] = f2bf(kf.x); o4[1] = f2bf(kf.y);
                o4[2] = f2bf(kf.z); o4[3] = f2bf(kf.w);
                *(u16x4*)&Klds[r][c] = o4;
                Vtld[c + 0][r] = f2bf(vf.x);
                Vtld[c + 1][r] = f2bf(vf.y);
                Vtld[c + 2][r] = f2bf(vf.z);
                Vtld[c + 3][r] = f2bf(vf.w);
            }
            for (int idx = tid; idx < DH * 32; idx += 512) {
                const int d_ = idx >> 5;
                const int col = (clen & ~31) + (idx & 31);
                if (col >= clen && col < cl32) Vtld[d_][col] = 0;
            }
            __syncthreads();

            if (gid >= 0) {
                for (int t = 0; t < ctiles; ++t) {
                    const int kb = t << 5;
                    short8 bk[2][2];
                    #pragma unroll
                    for (int kh = 0; kh < 2; ++kh)
                        #pragma unroll
                        for (int kc = 0; kc < 2; ++kc)
                            bk[kh][kc] = *(const short8*)&Klds[kb + kh * 16 + l15][lg * 8 + kc * 32];

                    f32x4 sa0 = (f32x4){-SHIFT, -SHIFT, -SHIFT, -SHIFT};
                    f32x4 sa1 = (f32x4){-SHIFT, -SHIFT, -SHIFT, -SHIFT};
                    __builtin_amdgcn_s_setprio(1);
                    sa0 = MFMA16(bk[0][0], aq[0], sa0, 0, 0, 0);
                    sa0 = MFMA16(bk[0][1], aq[1], sa0, 0, 0, 0);
                    sa1 = MFMA16(bk[1][0], aq[0], sa1, 0, 0, 0);
                    sa1 = MFMA16(bk[1][1], aq[1], sa1, 0, 0, 0);
                    __builtin_amdgcn_s_setprio(0);

                    float p0[4], p1[4];
                    #pragma unroll
                    for (int i = 0; i < 4; ++i) {
                        const int key0 = kb + lg * 4 + i;
                        const float x0 = (key0 < clen)      ? sa0[i] : MASKVAL;
                        const float x1 = (key0 + 16 < clen) ? sa1[i] : MASKVAL;
                        p0[i] = __expf(x0);
                        p1[i] = __expf(x1);
                        lsum += p0[i] + p1[i];
                    }

                    const unsigned int a0 = (unsigned int)f2bf(p0[0]) | ((unsigned int)f2bf(p0[1]) << 16);
                    const unsigned int a1 = (unsigned int)f2bf(p0[2]) | ((unsigned int)f2bf(p0[3]) << 16);
                    const unsigned int b0w = (unsigned int)f2bf(p1[0]) | ((unsigned int)f2bf(p1[1]) << 16);
                    const unsigned int b1w = (unsigned int)f2bf(p1[2]) | ((unsigned int)f2bf(p1[3]) << 16);
                    const unsigned int t00 = __shfl((int)a0, src0);
                    const unsigned int t01 = __shfl((int)a1, src0);
                    const unsigned int t10 = __shfl((int)b0w, src0);
                    const unsigned int t11 = __shfl((int)b1w, src0);
                    const unsigned int u00 = __shfl((int)a0, src1);
                    const unsigned int u01 = __shfl((int)a1, src1);
                    const unsigned int u10 = __shfl((int)b0w, src1);
                    const unsigned int u11 = __shfl((int)b1w, src1);
                    u32x4 af;
                    af[0] = khsel ? t10 : t00;
                    af[1] = khsel ? t11 : t01;
                    af[2] = khsel ? u10 : u00;
                    af[3] = khsel ? u11 : u01;
                    const short8 pa = __builtin_bit_cast(short8, af);

                    short8 bv[4];
                    #pragma unroll
                    for (int db = 0; db < 4; ++db)
                        bv[db] = *(const short8*)&Vtld[db * 16 + l15][kb + lg * 8];

                    __builtin_amdgcn_s_setprio(1);
                    #pragma unroll
                    for (int db = 0; db < 4; ++db)
                        o_acc[db] = MFMA16(bv[db], pa, o_acc[db], 0, 0, 0);
                    __builtin_amdgcn_s_setprio(0);
                }
            }
        }

        if (gid >= 0) {
            float rs = lsum;
            rs += __shfl_xor(rs, 16);
            rs += __shfl_xor(rs, 32);
            const float inv = 1.0f / rs;
            const int qrow = qs + gid * 16 + l15;
            if (qrow < qe) {
                float* op = &Out[((size_t)h * N_TOK + qrow) * DH + lg * 4];
                #pragma unroll
                for (int db = 0; db < 4; ++db) {
                    float4 v;
                    v.x = o_acc[db][0] * inv;
                    v.y = o_acc[db][1] * inv;
                    v.z = o_acc[db][2] * inv;
                    v.w = o_acc[db][3] * inv;
                    *(float4*)(op + db * 16) = v;
                }
            }
        }
        lsum = 0.f;
    }
}

extern "C" void kernel_launch(void* const* d_in, const int* in_sizes, int n_in,
                              void* d_out, int out_size, void* d_ws, size_t ws_size,
                              hipStream_t stream) {
    const float* Q = (const float*)d_in[0];
    const float* K = (const float*)d_in[1];
    const float* V = (const float*)d_in[2];
    const int* doc = (const int*)d_in[3];
    float* out = (float*)d_out;

    const size_t kbf_bytes = (size_t)NH * N_TOK * DH * 2;   // 8,388,608
    const size_t vtb_bytes = (size_t)NH * DH * NTP * 2;     // 8,454,144
    const size_t bnds_off = kbf_bytes + vtb_bytes;
    const size_t need = bnds_off + 256;

    if (ws_size >= need) {
        u16* Kbf = (u16*)d_ws;
        u16* Vtb = (u16*)((char*)d_ws + kbf_bytes);
        int* bnds = (int*)((char*)d_ws + bnds_off);
        doc_prep<<<dim3(4097), 256, 0, stream>>>(K, V, doc, Kbf, Vtb, bnds);
        doc_attn_v19<<<dim3(4096), 64, 0, stream>>>(Q, Kbf, Vtb, bnds, out);
    } else {
        doc_attn_v16<<<dim3(1024), 512, 0, stream>>>(Q, K, V, doc, out);
    }
}

// Round 9
// 39.938 us; speedup vs baseline: 1.8277x; 1.8277x over previous
//
#include <hip/hip_runtime.h>
#include <hip/hip_bf16.h>

typedef __attribute__((ext_vector_type(8))) short short8;
typedef __attribute__((ext_vector_type(4))) float f32x4;
typedef __attribute__((ext_vector_type(4))) unsigned int u32x4;
typedef __attribute__((ext_vector_type(4))) unsigned short u16x4;
typedef unsigned short u16;

#define MFMA16 __builtin_amdgcn_mfma_f32_16x16x32_bf16

__device__ __forceinline__ u16 f2bf(float x) {
    unsigned int u = __builtin_bit_cast(unsigned int, x);
    u = (u + 0x7FFFu + ((u >> 16) & 1u)) >> 16;
    return (u16)u;
}

// async global->LDS, 16B per lane; LDS dest = wave-uniform base + lane*16
__device__ __forceinline__ void gll16(const void* g, void* l) {
    __builtin_amdgcn_global_load_lds(
        (const __attribute__((address_space(1))) unsigned int*)g,
        (__attribute__((address_space(3))) unsigned int*)l, 16, 0, 0);
}

constexpr int N_TOK = 4096;
constexpr int DH = 64;
constexpr int NH = 16;
constexpr float SCALE = 0.125f;
constexpr float SHIFT = 8.0f;     // fixed softmax shift; exp(s-8), sums merge additively
constexpr float MASKVAL = -1e30f;

// ws layouts (bf16, XOR-swizzled at 16B-slot granularity so that a LINEAR
// global_load_lds copy + swizzled LDS reads are conflict-free):
//  Kws[h][key][slot^(key&7)]           : [16][4096][64] u16  (row = 128B)
//  Vws[h][chunk][dim][(kslot^(dim&7))] : [16][32][64][128] u16 (chunk = 16KB flat)
// Main staging is a flat 16KB copy per chunk for each of K and V.

// ============================ PREPASS =====================================
__global__ __launch_bounds__(256)
void doc_prep2(const float* __restrict__ Kg, const float* __restrict__ Vg,
               const int* __restrict__ doc, u16* __restrict__ Kws,
               u16* __restrict__ Vws, int* __restrict__ bnds) {
    const int b = blockIdx.x;
    const int tid = threadIdx.x;
    if (b < 2048) {
        // V: 32-key x 64-dim tile -> transpose -> swizzled chunk-major layout
        __shared__ u16 tile[DH][40];
        const int h = b >> 7, k0 = (b & 127) * 32;
        #pragma unroll
        for (int i = 0; i < 2; ++i) {
            const int idx = tid + i * 256;
            const int r = idx >> 4, c = (idx & 15) * 4;
            const float4 f = *(const float4*)&Vg[((size_t)h * N_TOK + k0 + r) * DH + c];
            tile[c + 0][r] = f2bf(f.x); tile[c + 1][r] = f2bf(f.y);
            tile[c + 2][r] = f2bf(f.z); tile[c + 3][r] = f2bf(f.w);
        }
        __syncthreads();
        #pragma unroll
        for (int i = 0; i < 2; ++i) {
            const int idx = tid + i * 256;
            const int d = idx >> 3, kq = (idx & 7) * 4;   // dim d, key quad
            const int k = k0 + kq;
            const int sp = ((k >> 3) & 15) ^ (d & 7);     // swizzled 16B key-slot
            const int dstk = (sp << 3) | (k & 7);
            u16x4 o;
            o[0] = tile[d][kq + 0]; o[1] = tile[d][kq + 1];
            o[2] = tile[d][kq + 2]; o[3] = tile[d][kq + 3];
            *(u16x4*)&Vws[((((size_t)h * 32 + (k >> 7)) * 64 + d) << 7) + dstk] = o;
        }
    } else if (b < 4096) {
        // K: bf16 convert + swizzled dim-slot within each 128B row
        const int bb = b - 2048;
        const int h = bb >> 7, k0 = (bb & 127) * 32;
        #pragma unroll
        for (int i = 0; i < 2; ++i) {
            const int idx = tid + i * 256;
            const int r = idx >> 4, c = (idx & 15) * 4;   // key r, dim quad c
            const int k = k0 + r;
            const float4 f = *(const float4*)&Kg[((size_t)h * N_TOK + k) * DH + c];
            const int dstc = (((c >> 3) ^ (k & 7)) << 3) | (c & 7);
            u16x4 o;
            o[0] = f2bf(f.x); o[1] = f2bf(f.y); o[2] = f2bf(f.z); o[3] = f2bf(f.w);
            *(u16x4*)&Kws[(((size_t)h << 12) + k) * 64 + dstc] = o;
        }
    } else {
        // doc-boundary scan -> bnds[17]
        if (tid < 17) bnds[tid] = N_TOK;
        __syncthreads();
        const int i0 = tid * 16;
        int prev = (i0 == 0) ? -1 : doc[i0 - 1];
        for (int j = 0; j < 16; ++j) {
            const int cur = doc[i0 + j];
            for (int dd = prev + 1; dd <= cur; ++dd) bnds[dd] = i0 + j;
            prev = cur;
        }
    }
}

// ============================ MAIN (v20) ==================================
// v16 compute core + async global_load_lds staging (zero staging registers,
// ~32KB in flight per block vs ~2KB before -> MLP-bound staging fixed) +
// absolute 128-aligned chunks with two-sided doc mask (v18-proven) + bounds
// from prepass (per-block scan deleted).
__global__ __launch_bounds__(512, 4)
void doc_attn_v20(const float* __restrict__ Qg, const u16* __restrict__ Kws,
                  const u16* __restrict__ Vws, const int* __restrict__ bnds,
                  float* __restrict__ Out) {
    __shared__ __align__(16) u16 Klin[128 * 64];   // 16KB, linear copy of Kws chunk
    __shared__ __align__(16) u16 Vlin[64 * 128];   // 16KB, linear copy of Vws chunk

    const int bid = blockIdx.x;                       // 0..1023
    const int swz = ((bid & 7) << 7) | (bid >> 3);    // XCD-chunked
    const int h = swz >> 6;
    const int dI = (swz >> 2) & 15;
    const int qq = swz & 3;                           // q-quarter
    const int tid = threadIdx.x;
    const int lane = tid & 63;
    const int w = tid >> 6;                           // wave 0..7
    const int l15 = lane & 15;
    const int lg = lane >> 4;

    const int qs = bnds[dI], qe = bnds[dI + 1];
    const int len = qe - qs;
    if (len <= 0) return;                             // uniform across block
    const int nG = (len + 15) >> 4;
    const int nGq = (nG + 3) >> 2;
    const int gBeg = qq * nGq;
    const int gEnd = min(nG, gBeg + nGq);
    if (gBeg >= gEnd) return;                         // uniform across block

    const int src0 = l15 + ((lane & 16) << 1);        // P^T exchange (v9-validated)
    const int src1 = src0 + 16;
    const bool khsel = (lg >> 1) != 0;
    const int rsw = l15 & 7;                          // read-side slot XOR

    const int C0beg = qs & ~127;

    for (int g0 = gBeg; g0 < gEnd; g0 += 8) {
        const int g = g0 + w;
        const int gid = (g < gEnd) ? g : -1;          // wave-uniform
        // Q fragment (fp32 -> bf16, SCALE folded)
        short8 aq[2];
        {
            const int gl = (g < gEnd) ? g : 0;
            const int qrow = min(qs + gl * 16 + l15, N_TOK - 1);  // clamp; never stored
            const float* qp = &Qg[((size_t)h * N_TOK + qrow) * DH + lg * 8];
            #pragma unroll
            for (int kc = 0; kc < 2; ++kc) {
                float4 f0 = *(const float4*)(qp + kc * 32);
                float4 f1 = *(const float4*)(qp + kc * 32 + 4);
                short8 a;
                a[0]=(short)f2bf(f0.x*SCALE); a[1]=(short)f2bf(f0.y*SCALE);
                a[2]=(short)f2bf(f0.z*SCALE); a[3]=(short)f2bf(f0.w*SCALE);
                a[4]=(short)f2bf(f1.x*SCALE); a[5]=(short)f2bf(f1.y*SCALE);
                a[6]=(short)f2bf(f1.z*SCALE); a[7]=(short)f2bf(f1.w*SCALE);
                aq[kc] = a;
            }
        }

        f32x4 o_acc[4];
        float lsum = 0.f;
        #pragma unroll
        for (int db = 0; db < 4; ++db) o_acc[db] = (f32x4){0.f, 0.f, 0.f, 0.f};

        // ---- chunk loop: absolute 128-key windows covering [qs, qe) ----
        for (int C0 = C0beg; C0 < qe; C0 += 128) {
            __syncthreads();   // previous chunk's LDS reads complete

            // flat async copy: 16KB K + 16KB V, 8 waves x (2+2) x 1KB
            const char* ksrc = (const char*)(Kws + (((size_t)h << 12) + C0) * 64);
            const char* vsrc = (const char*)(Vws + ((((size_t)h * 32 + (C0 >> 7)) * 64) << 7));
            #pragma unroll
            for (int j = 0; j < 2; ++j) {
                const int seg = w * 2 + j;
                gll16(ksrc + seg * 1024 + lane * 16, (char*)Klin + seg * 1024);
                gll16(vsrc + seg * 1024 + lane * 16, (char*)Vlin + seg * 1024);
            }
            __syncthreads();   // barrier drain (vmcnt 0) + visibility

            const int t0 = (qs > C0) ? ((qs - C0) >> 5) : 0;
            int t1 = (qe - C0 + 31) >> 5; if (t1 > 4) t1 = 4;

            if (gid >= 0) {
                for (int t = t0; t < t1; ++t) {
                    const int kb = t << 5;                   // chunk-rel key base
                    const int kabs = C0 + kb;                // absolute
                    // K fragments: row = kb+kh*16+l15, slot (lg+kc*4)^rsw
                    short8 bk[2][2];
                    #pragma unroll
                    for (int kh = 0; kh < 2; ++kh)
                        #pragma unroll
                        for (int kc = 0; kc < 2; ++kc)
                            bk[kh][kc] = *(const short8*)&Klin[(size_t)(kb + kh * 16 + l15) * 64
                                                + (((lg + kc * 4) ^ rsw) << 3)];

                    f32x4 sa0 = (f32x4){-SHIFT, -SHIFT, -SHIFT, -SHIFT};
                    f32x4 sa1 = (f32x4){-SHIFT, -SHIFT, -SHIFT, -SHIFT};
                    __builtin_amdgcn_s_setprio(1);
                    sa0 = MFMA16(bk[0][0], aq[0], sa0, 0, 0, 0);
                    sa0 = MFMA16(bk[0][1], aq[1], sa0, 0, 0, 0);
                    sa1 = MFMA16(bk[1][0], aq[0], sa1, 0, 0, 0);
                    sa1 = MFMA16(bk[1][1], aq[1], sa1, 0, 0, 0);
                    __builtin_amdgcn_s_setprio(0);

                    // fixed-shift softmax; two-sided doc mask (absolute keys)
                    float p0[4], p1[4];
                    #pragma unroll
                    for (int i = 0; i < 4; ++i) {
                        const int key0 = kabs + lg * 4 + i;
                        const int key1 = key0 + 16;
                        const float x0 = (key0 >= qs && key0 < qe) ? sa0[i] : MASKVAL;
                        const float x1 = (key1 >= qs && key1 < qe) ? sa1[i] : MASKVAL;
                        p0[i] = __expf(x0);
                        p1[i] = __expf(x1);
                        lsum += p0[i] + p1[i];
                    }

                    // P^T B-fragment via f2bf pack + cross-lg shuffles (v9-validated)
                    const unsigned int a0 = (unsigned int)f2bf(p0[0]) | ((unsigned int)f2bf(p0[1]) << 16);
                    const unsigned int a1 = (unsigned int)f2bf(p0[2]) | ((unsigned int)f2bf(p0[3]) << 16);
                    const unsigned int b0w = (unsigned int)f2bf(p1[0]) | ((unsigned int)f2bf(p1[1]) << 16);
                    const unsigned int b1w = (unsigned int)f2bf(p1[2]) | ((unsigned int)f2bf(p1[3]) << 16);
                    const unsigned int t00 = __shfl((int)a0, src0);
                    const unsigned int t01 = __shfl((int)a1, src0);
                    const unsigned int t10 = __shfl((int)b0w, src0);
                    const unsigned int t11 = __shfl((int)b1w, src0);
                    const unsigned int u00 = __shfl((int)a0, src1);
                    const unsigned int u01 = __shfl((int)a1, src1);
                    const unsigned int u10 = __shfl((int)b0w, src1);
                    const unsigned int u11 = __shfl((int)b1w, src1);
                    u32x4 af;
                    af[0] = khsel ? t10 : t00;
                    af[1] = khsel ? t11 : t01;
                    af[2] = khsel ? u10 : u00;
                    af[3] = khsel ? u11 : u01;
                    const short8 pa = __builtin_bit_cast(short8, af);

                    // V^T fragments: row = db*16+l15, slot ((kb>>3)+lg)^rsw
                    short8 bv[4];
                    #pragma unroll
                    for (int db = 0; db < 4; ++db)
                        bv[db] = *(const short8*)&Vlin[(size_t)(db * 16 + l15) * 128
                                        + ((((kb >> 3) + lg) ^ rsw) << 3)];

                    __builtin_amdgcn_s_setprio(1);
                    #pragma unroll
                    for (int db = 0; db < 4; ++db)
                        o_acc[db] = MFMA16(bv[db], pa, o_acc[db], 0, 0, 0);
                    __builtin_amdgcn_s_setprio(0);
                }
            }
        }

        // ---- epilogue: row-sum reduce (lanes share q across lg) ----
        if (gid >= 0) {
            float rs = lsum;
            rs += __shfl_xor(rs, 16);
            rs += __shfl_xor(rs, 32);
            const float inv = 1.0f / rs;
            const int qrow = qs + gid * 16 + l15;
            if (qrow < qe) {
                float* op = &Out[((size_t)h * N_TOK + qrow) * DH + lg * 4];
                #pragma unroll
                for (int db = 0; db < 4; ++db) {
                    float4 v;
                    v.x = o_acc[db][0] * inv;
                    v.y = o_acc[db][1] * inv;
                    v.z = o_acc[db][2] * inv;
                    v.w = o_acc[db][3] * inv;
                    *(float4*)(op + db * 16) = v;
                }
            }
        }
    }
}

// ==================== FALLBACK (v16 verbatim, 41.6us) =====================
constexpr int KMAXF = 128;
constexpr int KSTF = 72;
constexpr int VSTF = 136;

__global__ __launch_bounds__(512, 4)
void doc_attn_v16(const float* __restrict__ Qg, const float* __restrict__ Kg,
                  const float* __restrict__ Vg, const int* __restrict__ doc,
                  float* __restrict__ Out) {
    __shared__ __align__(16) u16 Klds[KMAXF][KSTF];
    __shared__ __align__(16) u16 Vtld[DH][VSTF];
    __shared__ int bnd[2];

    const int bid = blockIdx.x;
    const int swz = ((bid & 7) << 7) | (bid >> 3);
    const int h = swz >> 6;
    const int dI = (swz >> 2) & 15;
    const int qq = swz & 3;
    const int tid = threadIdx.x;
    const int lane = tid & 63;
    const int w = tid >> 6;
    const int l15 = lane & 15;
    const int lg = lane >> 4;

    if (tid == 0) { bnd[0] = N_TOK; bnd[1] = N_TOK; }
    __syncthreads();
    {
        const int i0 = tid * 8;
        int prev = (i0 == 0) ? -1 : doc[i0 - 1];
        #pragma unroll
        for (int j = 0; j < 8; ++j) {
            const int cur = doc[i0 + j];
            if (cur >= dI && prev < dI) bnd[0] = i0 + j;
            if (cur >= dI + 1 && prev < dI + 1) bnd[1] = i0 + j;
            prev = cur;
        }
    }
    __syncthreads();
    const int qs = bnd[0], qe = bnd[1];
    const int len = qe - qs;
    if (len <= 0) return;

    const int nG = (len + 15) >> 4;
    const int nGq = (nG + 3) >> 2;
    const int gBeg = qq * nGq;
    const int gEnd = min(nG, gBeg + nGq);
    if (gBeg >= gEnd) return;

    const int src0 = l15 + ((lane & 16) << 1);
    const int src1 = src0 + 16;
    const bool khsel = (lg >> 1) != 0;

    for (int g0 = gBeg; g0 < gEnd; g0 += 8) {
        const int g = g0 + w;
        const int gid = (g < gEnd) ? g : -1;
        short8 aq[2];
        {
            const int gl = (g < gEnd) ? g : 0;
            const int qrow = min(qs + gl * 16 + l15, N_TOK - 1);
            const float* qp = &Qg[((size_t)h * N_TOK + qrow) * DH + lg * 8];
            #pragma unroll
            for (int kc = 0; kc < 2; ++kc) {
                float4 f0 = *(const float4*)(qp + kc * 32);
                float4 f1 = *(const float4*)(qp + kc * 32 + 4);
                short8 a;
                a[0]=(short)f2bf(f0.x*SCALE); a[1]=(short)f2bf(f0.y*SCALE);
                a[2]=(short)f2bf(f0.z*SCALE); a[3]=(short)f2bf(f0.w*SCALE);
                a[4]=(short)f2bf(f1.x*SCALE); a[5]=(short)f2bf(f1.y*SCALE);
                a[6]=(short)f2bf(f1.z*SCALE); a[7]=(short)f2bf(f1.w*SCALE);
                aq[kc] = a;
            }
        }

        f32x4 o_acc[4];
        float lsum = 0.f;
        #pragma unroll
        for (int db = 0; db < 4; ++db) o_acc[db] = (f32x4){0.f, 0.f, 0.f, 0.f};

        for (int c0 = 0; c0 < len; c0 += KMAXF) {
            const int clen = min(KMAXF, len - c0);
            const int ctiles = (clen + 31) >> 5;
            const int cl32 = ctiles << 5;

            __syncthreads();

            for (int idx = tid; idx < clen * 16; idx += 512) {
                const int r = idx >> 4, c = (idx & 15) * 4;
                const float4 kf = *(const float4*)&Kg[((size_t)h * N_TOK + qs + c0 + r) * DH + c];
                const float4 vf = *(const float4*)&Vg[((size_t)h * N_TOK + qs + c0 + r) * DH + c];
                u16x4 o4;
                o4[0] = f2bf(kf.x); o4[1] = f2bf(kf.y);
                o4[2] = f2bf(kf.z); o4[3] = f2bf(kf.w);
                *(u16x4*)&Klds[r][c] = o4;
                Vtld[c + 0][r] = f2bf(vf.x);
                Vtld[c + 1][r] = f2bf(vf.y);
                Vtld[c + 2][r] = f2bf(vf.z);
                Vtld[c + 3][r] = f2bf(vf.w);
            }
            for (int idx = tid; idx < DH * 32; idx += 512) {
                const int d_ = idx >> 5;
                const int col = (clen & ~31) + (idx & 31);
                if (col >= clen && col < cl32) Vtld[d_][col] = 0;
            }
            __syncthreads();

            if (gid >= 0) {
                for (int t = 0; t < ctiles; ++t) {
                    const int kb = t << 5;
                    short8 bk[2][2];
                    #pragma unroll
                    for (int kh = 0; kh < 2; ++kh)
                        #pragma unroll
                        for (int kc = 0; kc < 2; ++kc)
                            bk[kh][kc] = *(const short8*)&Klds[kb + kh * 16 + l15][lg * 8 + kc * 32];

                    f32x4 sa0 = (f32x4){-SHIFT, -SHIFT, -SHIFT, -SHIFT};
                    f32x4 sa1 = (f32x4){-SHIFT, -SHIFT, -SHIFT, -SHIFT};
                    __builtin_amdgcn_s_setprio(1);
                    sa0 = MFMA16(bk[0][0], aq[0], sa0, 0, 0, 0);
                    sa0 = MFMA16(bk[0][1], aq[1], sa0, 0, 0, 0);
                    sa1 = MFMA16(bk[1][0], aq[0], sa1, 0, 0, 0);
                    sa1 = MFMA16(bk[1][1], aq[1], sa1, 0, 0, 0);
                    __builtin_amdgcn_s_setprio(0);

                    float p0[4], p1[4];
                    #pragma unroll
                    for (int i = 0; i < 4; ++i) {
                        const int key0 = kb + lg * 4 + i;
                        const float x0 = (key0 < clen)      ? sa0[i] : MASKVAL;
                        const float x1 = (key0 + 16 < clen) ? sa1[i] : MASKVAL;
                        p0[i] = __expf(x0);
                        p1[i] = __expf(x1);
                        lsum += p0[i] + p1[i];
                    }

                    const unsigned int a0 = (unsigned int)f2bf(p0[0]) | ((unsigned int)f2bf(p0[1]) << 16);
                    const unsigned int a1 = (unsigned int)f2bf(p0[2]) | ((unsigned int)f2bf(p0[3]) << 16);
                    const unsigned int b0w = (unsigned int)f2bf(p1[0]) | ((unsigned int)f2bf(p1[1]) << 16);
                    const unsigned int b1w = (unsigned int)f2bf(p1[2]) | ((unsigned int)f2bf(p1[3]) << 16);
                    const unsigned int t00 = __shfl((int)a0, src0);
                    const unsigned int t01 = __shfl((int)a1, src0);
                    const unsigned int t10 = __shfl((int)b0w, src0);
                    const unsigned int t11 = __shfl((int)b1w, src0);
                    const unsigned int u00 = __shfl((int)a0, src1);
                    const unsigned int u01 = __shfl((int)a1, src1);
                    const unsigned int u10 = __shfl((int)b0w, src1);
                    const unsigned int u11 = __shfl((int)b1w, src1);
                    u32x4 af;
                    af[0] = khsel ? t10 : t00;
                    af[1] = khsel ? t11 : t01;
                    af[2] = khsel ? u10 : u00;
                    af[3] = khsel ? u11 : u01;
                    const short8 pa = __builtin_bit_cast(short8, af);

                    short8 bv[4];
                    #pragma unroll
                    for (int db = 0; db < 4; ++db)
                        bv[db] = *(const short8*)&Vtld[db * 16 + l15][kb + lg * 8];

                    __builtin_amdgcn_s_setprio(1);
                    #pragma unroll
                    for (int db = 0; db < 4; ++db)
                        o_acc[db] = MFMA16(bv[db], pa, o_acc[db], 0, 0, 0);
                    __builtin_amdgcn_s_setprio(0);
                }
            }
        }

        if (gid >= 0) {
            float rs = lsum;
            rs += __shfl_xor(rs, 16);
            rs += __shfl_xor(rs, 32);
            const float inv = 1.0f / rs;
            const int qrow = qs + gid * 16 + l15;
            if (qrow < qe) {
                float* op = &Out[((size_t)h * N_TOK + qrow) * DH + lg * 4];
                #pragma unroll
                for (int db = 0; db < 4; ++db) {
                    float4 v;
                    v.x = o_acc[db][0] * inv;
                    v.y = o_acc[db][1] * inv;
                    v.z = o_acc[db][2] * inv;
                    v.w = o_acc[db][3] * inv;
                    *(float4*)(op + db * 16) = v;
                }
            }
        }
        lsum = 0.f;
    }
}

extern "C" void kernel_launch(void* const* d_in, const int* in_sizes, int n_in,
                              void* d_out, int out_size, void* d_ws, size_t ws_size,
                              hipStream_t stream) {
    const float* Q = (const float*)d_in[0];
    const float* K = (const float*)d_in[1];
    const float* V = (const float*)d_in[2];
    const int* doc = (const int*)d_in[3];
    float* out = (float*)d_out;

    const size_t kws_bytes = (size_t)NH * N_TOK * 64 * 2;        // 8,388,608
    const size_t vws_bytes = (size_t)NH * 32 * 64 * 128 * 2;     // 8,388,608
    const size_t bnds_off = kws_bytes + vws_bytes;
    const size_t need = bnds_off + 256;

    if (ws_size >= need) {
        u16* Kws = (u16*)d_ws;
        u16* Vws = (u16*)((char*)d_ws + kws_bytes);
        int* bnds = (int*)((char*)d_ws + bnds_off);
        doc_prep2<<<dim3(4097), 256, 0, stream>>>(K, V, doc, Kws, Vws, bnds);
        doc_attn_v20<<<dim3(1024), 512, 0, stream>>>(Q, Kws, Vws, bnds, out);
    } else {
        doc_attn_v16<<<dim3(1024), 512, 0, stream>>>(Q, K, V, doc, out);
    }
}